// Round 3
// baseline (262.792 us; speedup 1.0000x reference)
//
#include <hip/hip_runtime.h>

// Encoding layer. B=16, C=512, N=4096, K=32.
// v4: occupancy attack. v1-v3 all land 75-88us with every pipe <10% busy at
// 2 blocks/CU (one-shot grid, ~85% stall). Changes:
//  - 1024 blocks x 64 tokens; LDS 80KB -> 43KB => 3 blocks/CU resident
//    (12 waves/CU) + grid > capacity for cross-block phase overlap.
//  - XC is a real 2-deep c-group double buffer [2][64c][68n] (17 KB).
//  - GEMM1 c-contraction split across wave pairs (wave = (c-half, token-tile)),
//    partial S reduced via 16 KB LDS stash. Softmax becomes fully lane-local
//    (each lane holds all 32 k's - zero shuffles).
//  - GEMM2 B-frags from 4-deep global register ring (x L3-hot), issued
//    before softmax. A-frags (cw) converted in-register from f32 (L2-hot).
// Partials 1024 x 64KB = 64 MiB -> reduce kernel.

#define B_ 16
#define C_ 512
#define N_ 4096
#define K_ 32
#define CHUNK 64                  // tokens per block
#define NCH (N_ / CHUNK)          // 64 chunks per batch
#define NBLK (B_ * NCH)           // 1024 blocks
#define XCN 68                    // XC n-stride (u16): 136 B (odd dword step)
#define WLS 40                    // Wl n-stride (u16): 80 B

typedef __attribute__((ext_vector_type(8))) short short8;
typedef __attribute__((ext_vector_type(16))) float floatx16;

__device__ inline unsigned short f2bf(float f) {
    union { float f; unsigned u; } v; v.f = f;
    unsigned r = v.u + 0x7FFFu + ((v.u >> 16) & 1u);  // RNE
    return (unsigned short)(r >> 16);
}

// LDS-drain-only barrier: keeps global prefetches (vmcnt) in flight.
__device__ inline void cbar() {
    __builtin_amdgcn_sched_barrier(0);
    asm volatile("s_waitcnt lgkmcnt(0)" ::: "memory");
    __builtin_amdgcn_s_barrier();
    __builtin_amdgcn_sched_barrier(0);
}

template <int USE_WS>
__global__ __launch_bounds__(256, 3)
void enc_kernel(const float* __restrict__ x,
                const float* __restrict__ cw,
                const float* __restrict__ scale,
                float* __restrict__ outp)
{
    __shared__ unsigned short XC[2][64 * XCN];   // x bf16 dbuf [buf][c][n], 17408 B
    __shared__ float Sp[4][K_ * 32];             // GEMM1 S wave-partials, 16384 B
    __shared__ unsigned short Wl[2][K_ * WLS];   // softmax w bf16 [tile][k][n], 5120 B
    __shared__ float xsqL[16][CHUNK];            // ||x_n||^2 partials by r, 4096 B
    __shared__ float csq[K_];
    __shared__ float scl[K_];

    const int tid  = threadIdx.x;
    const int wave = tid >> 6;
    const int lane = tid & 63;
    const int l31  = lane & 31;
    const int lh   = lane >> 5;
    const int half = wave >> 1;                  // c-half owned in GEMM1
    const int tile = wave & 1;                   // token-tile owned in GEMM1

    const int b     = blockIdx.x >> 6;
    const int chunk = blockIdx.x & (NCH - 1);
    const float* xb = x + (long)b * C_ * N_;

    // staging mapping: thread = (r = tid>>4, p = tid&15); per 64-c group it
    // loads 4 rows (c = g*64 + i*16 + r), each one float4 (tokens p*4..p*4+3).
    const int r = tid >> 4;
    const int p = tid & 15;
    const float* xrow = xb + chunk * CHUNK + p * 4;

    float4 s0[4], s1[4], s2[4];                  // 3-deep staging ring
#define XISSUE(buf_, g_)                                                       \
    { _Pragma("unroll")                                                        \
      for (int i = 0; i < 4; ++i)                                              \
          buf_[i] = *(const float4*)(xrow + (long)((g_) * 64 + i * 16 + r) * N_); }

    float xs0 = 0.f, xs1 = 0.f, xs2 = 0.f, xs3 = 0.f;
#define XWRITE(buf_, db_)                                                      \
    { _Pragma("unroll")                                                        \
      for (int i = 0; i < 4; ++i) {                                            \
          const float4 v = buf_[i];                                            \
          xs0 += v.x * v.x; xs1 += v.y * v.y;                                  \
          xs2 += v.z * v.z; xs3 += v.w * v.w;                                  \
          const unsigned lo = (unsigned)f2bf(v.x) | ((unsigned)f2bf(v.y) << 16);\
          const unsigned hi = (unsigned)f2bf(v.z) | ((unsigned)f2bf(v.w) << 16);\
          *(uint2*)&XC[db_][(i * 16 + r) * XCN + p * 4] = make_uint2(lo, hi);  \
      } }

    // GEMM1 A-fragments: f32 cw rows (L2-hot) converted in-register.
    const float* cwr = cw + l31 * C_ + lh * 8;
    short8 afA[4], afB[4];
#define AFLOADG(buf_, g_)                                                      \
    { _Pragma("unroll")                                                        \
      for (int s = 0; s < 4; ++s) {                                            \
          const float4 u0 = *(const float4*)(cwr + (g_) * 64 + s * 16);        \
          const float4 u1 = *(const float4*)(cwr + (g_) * 64 + s * 16 + 4);    \
          short8 t_;                                                           \
          t_[0] = (short)f2bf(u0.x); t_[1] = (short)f2bf(u0.y);                \
          t_[2] = (short)f2bf(u0.z); t_[3] = (short)f2bf(u0.w);                \
          t_[4] = (short)f2bf(u1.x); t_[5] = (short)f2bf(u1.y);                \
          t_[6] = (short)f2bf(u1.z); t_[7] = (short)f2bf(u1.w);                \
          buf_[s] = t_; } }

    // ---- prologue ----
    XISSUE(s0, 0)
    XISSUE(s1, 1)
    if (tid < K_) scl[tid] = scale[tid];
    {   // csq[k] = ||c_k||^2 (overlaps prefetch latency)
        const int k = tid >> 3, q = tid & 7;
        const float4* src = (const float4*)(cw + k * C_ + q * 64);
        float ssum = 0.f;
        #pragma unroll
        for (int i = 0; i < 16; ++i) {
            const float4 v = src[i];
            ssum += v.x*v.x + v.y*v.y + v.z*v.z + v.w*v.w;
        }
        ssum += __shfl_xor(ssum, 1);
        ssum += __shfl_xor(ssum, 2);
        ssum += __shfl_xor(ssum, 4);
        if (q == 0) csq[k] = ssum;
    }
    AFLOADG(afA, half * 4)        // first group of my c-half
    XWRITE(s0, 0)
    XISSUE(s2, 2)
    cbar();      // XC group 0 ready

    // ========== GEMM1: S_partial[k][n] over my c-half, group-pipelined ==========
    floatx16 S;
    #pragma unroll
    for (int i = 0; i < 16; ++i) S[i] = 0.f;

    #pragma unroll
    for (int g = 0; g < 8; ++g) {
        if (g + 3 < 8) {          // refill the ring slot freed at g-3
            if      ((g % 3) == 0) XISSUE(s0, g + 3)
            else if ((g % 3) == 1) XISSUE(s1, g + 3)
            else                   XISSUE(s2, g + 3)
        }
        if ((g >> 2) == half) {   // this c-group belongs to my half
            if (((g + 1) >> 2) == half) {
                if (g & 1) AFLOADG(afA, g + 1) else AFLOADG(afB, g + 1)
            }
            #pragma unroll
            for (int s = 0; s < 4; ++s) {
                short8 bx;
                #pragma unroll
                for (int j = 0; j < 8; ++j)
                    bx[j] = (short)XC[g & 1][(s * 16 + lh * 8 + j) * XCN
                                            + tile * 32 + l31];
                S = __builtin_amdgcn_mfma_f32_32x32x16_bf16(
                        (g & 1) ? afB[s] : afA[s], bx, S, 0, 0, 0);
            }
        }
        if (g + 1 < 8) {
            if      (((g + 1) % 3) == 0) XWRITE(s0, (g + 1) & 1)
            else if (((g + 1) % 3) == 1) XWRITE(s1, (g + 1) & 1)
            else                         XWRITE(s2, (g + 1) & 1)
        }
        cbar();
    }

    // ---- stash: xsq partials, S partials; issue GEMM2 ring (4-deep) ----
    xsqL[r][p * 4 + 0] = xs0; xsqL[r][p * 4 + 1] = xs1;
    xsqL[r][p * 4 + 2] = xs2; xsqL[r][p * 4 + 3] = xs3;
    #pragma unroll
    for (int rr = 0; rr < 16; ++rr)
        Sp[wave][((rr & 3) + 8 * (rr >> 2) + 4 * lh) * 32 + l31] = S[rr];

    float4 bv[4][2];
#define G2LOAD(bi_, i_)                                                        \
    { const int t_ = (i_) >> 2, st_ = (i_) & 3;                                \
      const int c_ = wave * 128 + t_ * 32 + l31;                               \
      const int no_ = st_ * 16 + lh * 8;                                       \
      const float* p_ = xb + (long)c_ * N_ + chunk * CHUNK + no_;              \
      bv[bi_][0] = *(const float4*)p_;                                         \
      bv[bi_][1] = *(const float4*)(p_ + 4); }
    G2LOAD(0, 0)
    G2LOAD(1, 1)
    G2LOAD(2, 2)
    G2LOAD(3, 3)
    cbar();      // xsqL + Sp ready

    // ---- softmax (waves 0,1; tile = wave): fully lane-local, all 32 k's ----
    if (wave < 2) {
        const int n = wave * 32 + l31;
        float xq = 0.f;
        #pragma unroll
        for (int rr = 0; rr < 16; ++rr) xq += xsqL[rr][n];
        float L[32], mx = -3.4e38f;
        #pragma unroll
        for (int k = 0; k < 32; ++k) {
            const float sv = Sp[wave][k * 32 + l31] + Sp[wave + 2][k * 32 + l31];
            L[k] = scl[k] * (xq - 2.f * sv + csq[k]);
            mx = fmaxf(mx, L[k]);
        }
        float sum = 0.f;
        #pragma unroll
        for (int k = 0; k < 32; ++k) { L[k] = __expf(L[k] - mx); sum += L[k]; }
        const float inv = 1.f / sum;
        #pragma unroll
        for (int k = 0; k < 32; ++k)
            Wl[wave][k * WLS + l31] = f2bf(L[k] * inv);
    }
    cbar();      // Wl handoff

    // ========== GEMM2: enc[k][c] = sum_n W[k][n] x[n][c], B from global ring ====
    short8 aw[4];
    #pragma unroll
    for (int s = 0; s < 4; ++s)
        aw[s] = *(const short8*)&Wl[s >> 1][l31 * WLS + (s & 1) * 16 + lh * 8];

    floatx16 wacc;
    #pragma unroll
    for (int i = 0; i < 16; ++i) wacc[i] = 0.f;
    {
        short8 ones;
        #pragma unroll
        for (int j = 0; j < 8; ++j) ones[j] = (short)0x3F80;
        #pragma unroll
        for (int s = 0; s < 4; ++s)
            wacc = __builtin_amdgcn_mfma_f32_32x32x16_bf16(aw[s], ones, wacc, 0, 0, 0);
    }

    floatx16 acc[4];
    #pragma unroll
    for (int t = 0; t < 4; ++t)
        #pragma unroll
        for (int i = 0; i < 16; ++i) acc[t][i] = 0.f;

    #pragma unroll
    for (int i = 0; i < 16; ++i) {               // i = t*4 + s
        const int bi = i & 3;
        const int t  = i >> 2, s = i & 3;
        const float4 v0 = bv[bi][0];
        const float4 v1 = bv[bi][1];
        short8 bx;
        bx[0] = (short)f2bf(v0.x); bx[1] = (short)f2bf(v0.y);
        bx[2] = (short)f2bf(v0.z); bx[3] = (short)f2bf(v0.w);
        bx[4] = (short)f2bf(v1.x); bx[5] = (short)f2bf(v1.y);
        bx[6] = (short)f2bf(v1.z); bx[7] = (short)f2bf(v1.w);
        acc[t] = __builtin_amdgcn_mfma_f32_32x32x16_bf16(aw[s], bx, acc[t], 0, 0, 0);
        if (i + 4 < 16) G2LOAD(bi, i + 4)
    }

    // ---- epilogue: val = acc - wsum[k]*cw[k][c] (f32 cw) ----
    float* dst = USE_WS ? (outp + (size_t)blockIdx.x * K_ * C_)
                        : (outp + (size_t)b * K_ * C_);
    #pragma unroll
    for (int t = 0; t < 4; ++t) {
        const int c = wave * 128 + t * 32 + l31;
        #pragma unroll
        for (int rr = 0; rr < 16; ++rr) {
            const int k = (rr & 3) + 8 * (rr >> 2) + 4 * lh;
            const float val = acc[t][rr] - wacc[rr] * cw[k * C_ + c];
            if (USE_WS) dst[k * C_ + c] = val;
            else        atomicAdd(dst + k * C_ + c, val);
        }
    }
}

// out[b][k][c] = sum_{ch<64} part[b*64+ch][k][c];  grid 256 x 256, float4
__global__ __launch_bounds__(256)
void reduce_kernel(const float4* __restrict__ part, float4* __restrict__ out)
{
    const int gid = blockIdx.x * 256 + threadIdx.x;   // 0..65535
    const int bb  = gid >> 12;                        // 4096 float4 per batch
    const int i4  = gid & 4095;
    const float4* pp = part + ((size_t)bb * NCH) * 4096 + i4;
    float4 s = make_float4(0.f, 0.f, 0.f, 0.f);
    #pragma unroll 8
    for (int j = 0; j < NCH; ++j) {
        const float4 v = pp[(size_t)j * 4096];
        s.x += v.x; s.y += v.y; s.z += v.z; s.w += v.w;
    }
    out[gid] = s;
}

extern "C" void kernel_launch(void* const* d_in, const int* in_sizes, int n_in,
                              void* d_out, int out_size, void* d_ws, size_t ws_size,
                              hipStream_t stream) {
    const float* x     = (const float*)d_in[0];
    const float* cw    = (const float*)d_in[1];
    const float* scale = (const float*)d_in[2];
    float* out = (float*)d_out;

    const size_t ws_need = (size_t)NBLK * K_ * C_ * sizeof(float);  // 64 MiB
    if (ws_size >= ws_need) {
        float* part = (float*)d_ws;
        hipLaunchKernelGGL(enc_kernel<1>, dim3(NBLK), dim3(256), 0, stream,
                           x, cw, scale, part);
        hipLaunchKernelGGL(reduce_kernel, dim3(256), dim3(256), 0, stream,
                           (const float4*)part, (float4*)out);
    } else {
        hipMemsetAsync(out, 0, (size_t)out_size * sizeof(float), stream);
        hipLaunchKernelGGL(enc_kernel<0>, dim3(NBLK), dim3(256), 0, stream,
                           x, cw, scale, out);
    }
}

// Round 4
// 223.270 us; speedup vs baseline: 1.1770x; 1.1770x over previous
//
#include <hip/hip_runtime.h>

// Encoding layer. B=16, C=512, N=4096, K=32.
// v5: barrier-free GEMM1. v0-v4 showed every staged-barrier variant lands at
// 77-119us with all pipes <27% busy: the ~11 lockstep barriers/chunk serialize
// all resident waves onto one LDS staging chain. Changes vs v0 (best, 77.5us):
//  - GEMM1 B-frags loaded directly global->register (8 per-lane dwords, each
//    instruction wave-coalesced 2x128B); x read once, no XC tile, no staging
//    ring, no barriers. A-frags (cw) converted f32->bf16 in-register (L2-hot).
//  - xsq accumulated in-register during the B loads (1 shuffle to finish).
//  - softmax per-wave on its own 32 tokens (v0 mapping).
//  - Only 2 barriers/block: csq/scl visibility + Wl handoff. Neither drains
//    vmcnt (lgkm-only), so the GEMM2 register ring survives them.
//  - GEMM2 / wacc / epilogue / reduce: v0's proven code (f32 cw in epilogue).
// LDS 10.5 KB; occupancy VGPR-bound only (launch_bounds(256,3)).

#define B_ 16
#define C_ 512
#define N_ 4096
#define K_ 32
#define CHUNK 128                 // tokens per block
#define NCH (N_ / CHUNK)          // 32 chunks per batch
#define NBLK (B_ * NCH)           // 512 blocks
#define WLS 40                    // Wl n-stride (u16): 80 B

typedef __attribute__((ext_vector_type(8))) short short8;
typedef __attribute__((ext_vector_type(16))) float floatx16;

__device__ inline unsigned short f2bf(float f) {
    union { float f; unsigned u; } v; v.f = f;
    unsigned r = v.u + 0x7FFFu + ((v.u >> 16) & 1u);  // RNE
    return (unsigned short)(r >> 16);
}

// LDS-drain-only barrier: keeps global loads (vmcnt) in flight across it.
__device__ inline void cbar() {
    __builtin_amdgcn_sched_barrier(0);
    asm volatile("s_waitcnt lgkmcnt(0)" ::: "memory");
    __builtin_amdgcn_s_barrier();
    __builtin_amdgcn_sched_barrier(0);
}

template <int USE_WS>
__global__ __launch_bounds__(256, 3)
void enc_kernel(const float* __restrict__ x,
                const float* __restrict__ cw,
                const float* __restrict__ scale,
                float* __restrict__ outp)
{
    __shared__ unsigned short Wl[4][K_ * WLS];   // softmax w bf16 [tile][k][n], 10240 B
    __shared__ float csq[K_];
    __shared__ float scl[K_];

    const int tid  = threadIdx.x;
    const int wave = tid >> 6;
    const int lane = tid & 63;
    const int l31  = lane & 31;
    const int lh   = lane >> 5;

    const int b     = blockIdx.x >> 5;           // NCH = 32
    const int chunk = blockIdx.x & (NCH - 1);
    const float* xb = x + (long)b * C_ * N_;

    // ---- prologue: scale + csq ----
    if (tid < K_) scl[tid] = scale[tid];
    {
        const int k = tid >> 3, q = tid & 7;      // k row, 64-c slice
        const float4* src = (const float4*)(cw + k * C_ + q * 64);
        float ssum = 0.f;
        #pragma unroll
        for (int i = 0; i < 16; ++i) {
            const float4 v = src[i];
            ssum += v.x*v.x + v.y*v.y + v.z*v.z + v.w*v.w;
        }
        ssum += __shfl_xor(ssum, 1);
        ssum += __shfl_xor(ssum, 2);
        ssum += __shfl_xor(ssum, 4);
        if (q == 0) csq[k] = ssum;
    }

    // ========== GEMM1: S[k][n] = cw @ x, direct global->register, no LDS ======
    // wave owns tokens n = chunk*128 + wave*32 + l31; contraction c walks 8
    // 64-c groups. B-frag element j: x[c0+j][n] (per-lane dword, wave-coalesced).
    const float* xcol = xb + chunk * CHUNK + wave * 32 + l31;
    const float* cwr  = cw + l31 * C_ + lh * 8;

    short8 afA[4], afB[4];
#define AFLOADG(buf_, ptr_)                                                    \
    { _Pragma("unroll")                                                        \
      for (int s = 0; s < 4; ++s) {                                            \
          const float4 u0 = *(const float4*)((ptr_) + s * 16);                 \
          const float4 u1 = *(const float4*)((ptr_) + s * 16 + 4);             \
          short8 t_;                                                           \
          t_[0] = (short)f2bf(u0.x); t_[1] = (short)f2bf(u0.y);                \
          t_[2] = (short)f2bf(u0.z); t_[3] = (short)f2bf(u0.w);                \
          t_[4] = (short)f2bf(u1.x); t_[5] = (short)f2bf(u1.y);                \
          t_[6] = (short)f2bf(u1.z); t_[7] = (short)f2bf(u1.w);                \
          buf_[s] = t_; } }

    floatx16 S;
    #pragma unroll
    for (int i = 0; i < 16; ++i) S[i] = 0.f;
    float xs = 0.f;

    AFLOADG(afA, cwr)
    #pragma unroll 2
    for (int g = 0; g < 8; ++g) {
        const float* xg = xcol + (long)g * 64 * N_;
        if (g + 1 < 8) {
            if (g & 1) AFLOADG(afA, cwr + (g + 1) * 64)
            else       AFLOADG(afB, cwr + (g + 1) * 64)
        }
        #pragma unroll
        for (int s = 0; s < 4; ++s) {
            float xv[8];
            #pragma unroll
            for (int j = 0; j < 8; ++j)
                xv[j] = xg[(long)(s * 16 + lh * 8 + j) * N_];
            short8 bx;
            #pragma unroll
            for (int j = 0; j < 8; ++j) {
                xs += xv[j] * xv[j];
                bx[j] = (short)f2bf(xv[j]);
            }
            S = __builtin_amdgcn_mfma_f32_32x32x16_bf16(
                    (g & 1) ? afB[s] : afA[s], bx, S, 0, 0, 0);
        }
    }

    // lane pair (lh=0, lh=1) covered complementary halves of c for token l31
    xs += __shfl_xor(xs, 32);

    // ---- GEMM2 ring prefetch (independent of softmax; flies through it) ----
    float4 bv[6][2];
#define G2LOAD(bi_, i_)                                                        \
    { const int t_ = (i_) >> 3, st_ = (i_) & 7;                                \
      const int c_ = wave * 128 + t_ * 32 + l31;                               \
      const int no_ = (st_ >> 1) * 32 + (st_ & 1) * 16 + lh * 8;               \
      const float* p_ = xb + (long)c_ * N_ + chunk * CHUNK + no_;              \
      bv[bi_][0] = *(const float4*)p_;                                         \
      bv[bi_][1] = *(const float4*)(p_ + 4); }
    G2LOAD(0, 0)
    G2LOAD(1, 1)
    G2LOAD(2, 2)
    G2LOAD(3, 3)
    G2LOAD(4, 4)
    G2LOAD(5, 5)

    cbar();      // csq/scl visible (lgkm-only: ring stays in flight)

    // ---- softmax over k: lane pair (l31, l31+32) holds 16 k's each ----
    {
        const float xq = xs;
        float L[16], mx = -3.4e38f;
        #pragma unroll
        for (int rr = 0; rr < 16; ++rr) {
            const int k = (rr & 3) + 8 * (rr >> 2) + 4 * lh;
            L[rr] = scl[k] * (xq - 2.f * S[rr] + csq[k]);
            mx = fmaxf(mx, L[rr]);
        }
        mx = fmaxf(mx, __shfl_xor(mx, 32));
        float sum = 0.f;
        #pragma unroll
        for (int rr = 0; rr < 16; ++rr) { L[rr] = __expf(L[rr] - mx); sum += L[rr]; }
        sum += __shfl_xor(sum, 32);
        const float inv = 1.f / sum;
        #pragma unroll
        for (int rr = 0; rr < 16; ++rr) {
            const int k = (rr & 3) + 8 * (rr >> 2) + 4 * lh;
            Wl[wave][k * WLS + l31] = f2bf(L[rr] * inv);
        }
    }
    cbar();      // Wl handoff

    // ========== GEMM2: enc[k][c] = sum_n W[k][n] x[n][c] ==========
    short8 aw[8];
    #pragma unroll
    for (int st = 0; st < 8; ++st)
        aw[st] = *(const short8*)&Wl[st >> 1][l31 * WLS + (st & 1) * 16 + lh * 8];

    floatx16 wacc;
    #pragma unroll
    for (int i = 0; i < 16; ++i) wacc[i] = 0.f;
    {
        short8 ones;
        #pragma unroll
        for (int j = 0; j < 8; ++j) ones[j] = (short)0x3F80;
        #pragma unroll
        for (int st = 0; st < 8; ++st)
            wacc = __builtin_amdgcn_mfma_f32_32x32x16_bf16(aw[st], ones, wacc, 0, 0, 0);
    }

    floatx16 acc[4];
    #pragma unroll
    for (int t = 0; t < 4; ++t)
        #pragma unroll
        for (int i = 0; i < 16; ++i) acc[t][i] = 0.f;

    #pragma unroll
    for (int i = 0; i < 32; ++i) {               // i = t*8 + st
        const int bi = i % 6;
        const int t  = i >> 3, st = i & 7;
        const float4 v0 = bv[bi][0];
        const float4 v1 = bv[bi][1];
        short8 bx;
        bx[0] = (short)f2bf(v0.x); bx[1] = (short)f2bf(v0.y);
        bx[2] = (short)f2bf(v0.z); bx[3] = (short)f2bf(v0.w);
        bx[4] = (short)f2bf(v1.x); bx[5] = (short)f2bf(v1.y);
        bx[6] = (short)f2bf(v1.z); bx[7] = (short)f2bf(v1.w);
        acc[t] = __builtin_amdgcn_mfma_f32_32x32x16_bf16(aw[st], bx, acc[t], 0, 0, 0);
        if (i + 6 < 32) G2LOAD(bi, i + 6)
    }

    // ---- epilogue: val = acc - wsum[k]*cw[k][c] (f32 cw) ----
    float* dst = USE_WS ? (outp + (size_t)blockIdx.x * K_ * C_)
                        : (outp + (size_t)b * K_ * C_);
    #pragma unroll
    for (int t = 0; t < 4; ++t) {
        const int c = wave * 128 + t * 32 + l31;
        #pragma unroll
        for (int rr = 0; rr < 16; ++rr) {
            const int k = (rr & 3) + 8 * (rr >> 2) + 4 * lh;
            const float val = acc[t][rr] - wacc[rr] * cw[k * C_ + c];
            if (USE_WS) dst[k * C_ + c] = val;
            else        atomicAdd(dst + k * C_ + c, val);
        }
    }
}

// out[b][k][c] = sum_{ch<32} part[b*32+ch][k][c];  grid 256 x 256, float4
__global__ __launch_bounds__(256)
void reduce_kernel(const float4* __restrict__ part, float4* __restrict__ out)
{
    const int gid = blockIdx.x * 256 + threadIdx.x;   // 0..65535
    const int bb  = gid >> 12;                        // 4096 float4 per batch
    const int i4  = gid & 4095;
    const float4* pp = part + ((size_t)bb * NCH) * 4096 + i4;
    float4 s = make_float4(0.f, 0.f, 0.f, 0.f);
    #pragma unroll
    for (int j = 0; j < NCH; ++j) {
        const float4 v = pp[(size_t)j * 4096];
        s.x += v.x; s.y += v.y; s.z += v.z; s.w += v.w;
    }
    out[gid] = s;
}

extern "C" void kernel_launch(void* const* d_in, const int* in_sizes, int n_in,
                              void* d_out, int out_size, void* d_ws, size_t ws_size,
                              hipStream_t stream) {
    const float* x     = (const float*)d_in[0];
    const float* cw    = (const float*)d_in[1];
    const float* scale = (const float*)d_in[2];
    float* out = (float*)d_out;

    const size_t ws_need = (size_t)NBLK * K_ * C_ * sizeof(float);  // 32 MiB
    if (ws_size >= ws_need) {
        float* part = (float*)d_ws;
        hipLaunchKernelGGL(enc_kernel<1>, dim3(NBLK), dim3(256), 0, stream,
                           x, cw, scale, part);
        hipLaunchKernelGGL(reduce_kernel, dim3(256), dim3(256), 0, stream,
                           (const float4*)part, (float4*)out);
    } else {
        hipMemsetAsync(out, 0, (size_t)out_size * sizeof(float), stream);
        hipLaunchKernelGGL(enc_kernel<0>, dim3(NBLK), dim3(256), 0, stream,
                           x, cw, scale, out);
    }
}